// Round 4
// baseline (1121.866 us; speedup 1.0000x reference)
//
#include <hip/hip_runtime.h>

// PNA GNN (2 layers) on MI355X — bf16x3 MFMA GEMMs, dist-2 pipelined, CSR agg.
#define NODES 10000
#define EDGES 160000
#define FDIM 64
#define DDIM 32
#define HDIM 128
#define AVG_DEG_LOG 2.8332133440562162f   // log(17)
#define EPS_BN 1e-5f
#define EPS_STD 1e-5f

typedef short bf16x8 __attribute__((ext_vector_type(8)));   // 8 bf16 (4 VGPRs)
typedef unsigned short u16x8 __attribute__((ext_vector_type(8)));
typedef float f32x4  __attribute__((ext_vector_type(4)));   // 4 fp32

struct GArgs {
  const float* A;
  const float* s0;
  const float* s1;
  const int*   i0;
  const int*   i1;
  const float* agg;
  const float* fs;
  const float* invfs;
  const float* B;             // fp32 B for the small weight-combine GEMM
  const unsigned short* Bph;  // prepped bf16-hi fragments
  const unsigned short* Bpl;  // prepped bf16-lo fragments
  const float* bias;
  float*       C;
  int M, K;
};

// ---------------- bf16 helpers ----------------
__device__ __forceinline__ unsigned short f2bf(float x){   // round-to-nearest-even
  unsigned u = __float_as_uint(x);
  return (unsigned short)((u + 0x7FFFu + ((u >> 16) & 1u)) >> 16);
}
__device__ __forceinline__ float bf2f(unsigned short h){
  return __uint_as_float(((unsigned)h) << 16);
}

// ===========================================================================
// MFMA GEMM: C[M,128] = gatherA[M,K] @ W[K,128] + bias, bf16 hi/lo split
// (3 MFMAs: ah*bh + ah*bl + al*bh; truncation split, error ~2^-15 rel).
// 512 threads (8 waves): wave rq=w>>1 owns a 32-row quarter (2 frags),
// ch=w&1 owns a 64-col half (4 frags). BM=128, BK=32.
// Schedule: 1 barrier/step, global->reg prefetch distance 2, LDS dbuf,
// B-fragments loaded from prepped global (L2) at step top.
// AMODE 0: direct [M,K]; 1: [s0[i0], s1[i1], A]; 2: [A | agg | agg*fs | agg/f]
// EPI 0: store; 1: relu-store; 2: C += 0.5*(acc+bias).
// ===========================================================================
#define ASTR 40   // 32 + 8 pad shorts = 80 B row stride

template<int AMODE, int EPI>
__global__ __launch_bounds__(512, 4) void mgemm_k(GArgs g){
  __shared__ unsigned short Ah[2][128 * ASTR];
  __shared__ unsigned short Al[2][128 * ASTR];
  const int tid  = threadIdx.x;
  const int row0 = blockIdx.y * 128;
  const int wave = tid >> 6, lane = tid & 63;
  const int rq = wave >> 1, ch = wave & 1;
  const int lrow = lane & 15, lk = lane >> 4;

  // --- per-thread staging context: row fixed for the whole kernel ---
  const int srow = tid >> 2;            // 0..127
  const int c0   = (tid & 3) << 3;      // float offset within 32-wide K tile
  const int gr   = row0 + srow;
  const bool valid = gr < g.M;
  const int gi = valid ? gr : 0;
  const float* p0; const float* p1; const float* p2;
  float f1 = 1.f, f2 = 1.f;
  if constexpr (AMODE == 0){
    p0 = g.A + (size_t)gi * g.K; p1 = p0; p2 = p0;
  } else if constexpr (AMODE == 1){
    p0 = g.s0 + (size_t)g.i0[gi] * HDIM;
    p1 = g.s1 + (size_t)g.i1[gi] * HDIM;
    p2 = g.A  + (size_t)gi * HDIM;
  } else {
    p0 = g.A   + (size_t)gi * HDIM;
    p1 = g.agg + (size_t)gi * 512;
    p2 = p1;
    f1 = g.fs[gi]; f2 = g.invfs[gi];
  }

  auto ld8 = [&](int k0, float4& a, float4& b){
    if (!valid){ a = make_float4(0.f,0.f,0.f,0.f); b = a; return; }
    const int kk = k0 + c0;
    const float* p; float sc = 1.f;
    if constexpr (AMODE == 0){
      p = p0 + kk;
    } else if constexpr (AMODE == 1){
      p = (kk < HDIM) ? (p0 + kk) : (kk < 2*HDIM) ? (p1 + kk - HDIM) : (p2 + kk - 2*HDIM);
    } else {
      if (kk < HDIM){ p = p0 + kk; }
      else {
        const int q = kk - HDIM;
        p = p1 + (q & 511);
        const int seg = q >> 9;
        sc = (seg == 0) ? 1.f : (seg == 1) ? f1 : f2;
      }
    }
    const float4* p4 = (const float4*)p;
    a = p4[0]; b = p4[1];
    if constexpr (AMODE == 2){
      if (sc != 1.f){
        a.x*=sc; a.y*=sc; a.z*=sc; a.w*=sc;
        b.x*=sc; b.y*=sc; b.z*=sc; b.w*=sc;
      }
    }
  };

  auto st8 = [&](int buf, const float4& a, const float4& b){
    const int base = srow * ASTR + c0;
    const float vv[8] = {a.x,a.y,a.z,a.w,b.x,b.y,b.z,b.w};
    u16x8 h8, l8;
    #pragma unroll
    for (int j = 0; j < 8; j++){
      const unsigned u = __float_as_uint(vv[j]);
      h8[j] = (unsigned short)(u >> 16);                       // trunc hi
      const float rem = vv[j] - __uint_as_float(u & 0xFFFF0000u);
      l8[j] = (unsigned short)(__float_as_uint(rem) >> 16);    // trunc lo
    }
    *(u16x8*)&Ah[buf][base] = h8;
    *(u16x8*)&Al[buf][base] = l8;
  };

  const int nsteps = g.K >> 5;
  float4 va, vb, wa, wb;
  ld8(0, va, vb);
  st8(0, va, vb);
  if (nsteps > 1) ld8(32, wa, wb);
  __syncthreads();

  f32x4 acc[2][4] = {};

  for (int s = 0; s < nsteps; s++){
    const int cur = s & 1;
    // B fragments for this step: issue ASAP (L2-hot, identical across blocks)
    bf16x8 bh[4], bl[4];
    const size_t bbase = ((size_t)s * 8 + ch * 4) * 512 + (size_t)lane * 8;
    #pragma unroll
    for (int nf = 0; nf < 4; nf++){
      bh[nf] = *(const bf16x8*)(g.Bph + bbase + (size_t)nf * 512);
      bl[nf] = *(const bf16x8*)(g.Bpl + bbase + (size_t)nf * 512);
    }
    // write next LDS buffer (its loads were issued >=1 full iter ago),
    // then launch the distance-2 load into the freed registers
    if (s + 1 < nsteps){
      st8(cur ^ 1, wa, wb);
      if (s + 2 < nsteps) ld8((s + 2) << 5, wa, wb);
    }
    // compute on cur
    #pragma unroll
    for (int mf = 0; mf < 2; mf++){
      const int ao = (rq*32 + mf*16 + lrow) * ASTR + lk * 8;
      bf16x8 ah  = *(const bf16x8*)&Ah[cur][ao];
      bf16x8 alo = *(const bf16x8*)&Al[cur][ao];
      #pragma unroll
      for (int nf = 0; nf < 4; nf++){
        acc[mf][nf] = __builtin_amdgcn_mfma_f32_16x16x32_bf16(ah,  bh[nf], acc[mf][nf], 0, 0, 0);
        acc[mf][nf] = __builtin_amdgcn_mfma_f32_16x16x32_bf16(ah,  bl[nf], acc[mf][nf], 0, 0, 0);
        acc[mf][nf] = __builtin_amdgcn_mfma_f32_16x16x32_bf16(alo, bh[nf], acc[mf][nf], 0, 0, 0);
      }
    }
    __syncthreads();
  }

  #pragma unroll
  for (int mf = 0; mf < 2; mf++){
    #pragma unroll
    for (int nf = 0; nf < 4; nf++){
      const int col = ch*64 + nf*16 + lrow;
      const float b = g.bias[col];
      #pragma unroll
      for (int j = 0; j < 4; j++){
        const int r = row0 + rq*32 + mf*16 + lk*4 + j;
        if (r < g.M){
          float val = acc[mf][nf][j] + b;
          if constexpr (EPI == 1) val = fmaxf(val, 0.f);
          float* cp = g.C + (size_t)r * HDIM + col;
          if constexpr (EPI == 2) val = *cp + 0.5f * val;
          *cp = val;
        }
      }
    }
  }
}

// ===========================================================================
// B-prep: fp32 W[K,128] -> fragment-ordered bf16 hi/lo arrays (rounded split).
// ===========================================================================
__global__ void bprep_k(const float* __restrict__ W, unsigned short* __restrict__ Bph,
                        unsigned short* __restrict__ Bpl){
  const int bb = blockIdx.x;           // kq*8 + n
  const int kq = bb >> 3, n = bb & 7;
  const int l = threadIdx.x;           // 64
  const int colg = n*16 + (l & 15);
  const int krow = kq*32 + (l >> 4)*8;
  float vv[8];
  #pragma unroll
  for (int i = 0; i < 8; i++) vv[i] = W[(size_t)(krow + i) * HDIM + colg];
  u16x8 h, lo;
  #pragma unroll
  for (int i = 0; i < 8; i++){
    h[i]  = f2bf(vv[i]);
    lo[i] = f2bf(vv[i] - bf2f(h[i]));
  }
  const size_t o = ((size_t)bb * 64 + l) * 8;
  *(u16x8*)&Bph[o] = h;
  *(u16x8*)&Bpl[o] = lo;
}

// ===========================================================================
// Small fp32 tiled GEMM for weight combining (M<=1664, K=128, N=128).
// ===========================================================================
template<int AMODE_UNUSED, int EPI_UNUSED>
__global__ __launch_bounds__(256) void gemm_k(GArgs g){
  __shared__ float As[16][68];
  __shared__ float Bs[16][68];
  const int tid = threadIdx.x;
  const int tx = tid & 15, ty = tid >> 4;
  const int row0 = blockIdx.y * 64, col0 = blockIdx.x * 64;
  float acc[4][4] = {};
  for (int k0 = 0; k0 < g.K; k0 += 16){
    #pragma unroll
    for (int i = 0; i < 4; i++){
      int l = tid + i * 256;
      int ar = l >> 4, ak = l & 15;
      int gr = row0 + ar;
      float v = 0.f;
      if (gr < g.M) v = g.A[(size_t)gr * g.K + k0 + ak];
      As[ak][ar] = v;
    }
    #pragma unroll
    for (int i = 0; i < 4; i++){
      int l = tid + i * 256;
      int bn_ = l & 63, bk = l >> 6;
      Bs[bk][bn_] = g.B[(size_t)(k0 + bk) * HDIM + col0 + bn_];
    }
    __syncthreads();
    #pragma unroll
    for (int kk = 0; kk < 16; kk++){
      float a[4], b[4];
      #pragma unroll
      for (int j = 0; j < 4; j++) a[j] = As[kk][ty*4 + j];
      #pragma unroll
      for (int j = 0; j < 4; j++) b[j] = Bs[kk][tx*4 + j];
      #pragma unroll
      for (int ii = 0; ii < 4; ii++)
        #pragma unroll
        for (int jj = 0; jj < 4; jj++)
          acc[ii][jj] = fmaf(a[ii], b[jj], acc[ii][jj]);
    }
    __syncthreads();
  }
  #pragma unroll
  for (int ii = 0; ii < 4; ii++){
    int gr = row0 + ty*4 + ii;
    if (gr >= g.M) continue;
    #pragma unroll
    for (int jj = 0; jj < 4; jj++)
      g.C[(size_t)gr * HDIM + col0 + tx*4 + jj] = acc[ii][jj];
  }
}

// ===========================================================================
// CSR build over dst (constant across layers): deg count -> scan -> fill.
// ===========================================================================
__global__ void deg_init_k(int* cnt, int* cursor){
  int i = blockIdx.x * 256 + threadIdx.x;
  if (i < NODES){ cnt[i] = 0; cursor[i] = 0; }
}
__global__ void deg_count_k(const int* __restrict__ dst, int* cnt){
  int e = blockIdx.x * 256 + threadIdx.x;
  if (e < EDGES) atomicAdd(&cnt[dst[e]], 1);
}
__global__ void deg_fin_k(const int* __restrict__ cnt, float* fdeg, float* invf){
  int i = blockIdx.x * 256 + threadIdx.x;
  if (i < NODES){
    float d = fmaxf((float)cnt[i], 1.f);
    float f = logf(d + 1.f) / AVG_DEG_LOG;
    fdeg[i] = f;
    invf[i] = 1.f / f;
  }
}
// Single-block exclusive scan of cnt[NODES] -> off[NODES] (+ off[NODES]=E).
__global__ __launch_bounds__(256) void scan_k(const int* __restrict__ cnt, int* __restrict__ off){
  __shared__ int sh[256];
  __shared__ int carry;
  if (threadIdx.x == 0) carry = 0;
  __syncthreads();
  for (int base = 0; base < NODES; base += 256){
    int i = base + threadIdx.x;
    int v = (i < NODES) ? cnt[i] : 0;
    sh[threadIdx.x] = v;
    __syncthreads();
    #pragma unroll
    for (int o = 1; o < 256; o <<= 1){
      int t = (threadIdx.x >= o) ? sh[threadIdx.x - o] : 0;
      __syncthreads();
      sh[threadIdx.x] += t;
      __syncthreads();
    }
    if (i < NODES) off[i] = carry + sh[threadIdx.x] - v;   // exclusive
    __syncthreads();
    if (threadIdx.x == 255) carry += sh[255];
    __syncthreads();
  }
  if (threadIdx.x == 0) off[NODES] = carry;
}
__global__ void csr_fill_k(const int* __restrict__ dst, const int* __restrict__ off,
                           int* cursor, int* __restrict__ eidx){
  int e = blockIdx.x * 256 + threadIdx.x;
  if (e < EDGES){
    int d = dst[e];
    int p = atomicAdd(&cursor[d], 1);
    eidx[off[d] + p] = e;
  }
}

// ===========================================================================
// CSR aggregation: block = 256 thr = 2 nodes x 128 cols. Fuses finalize.
// agg[node][0:512] = [mean | min | max | std]
// ===========================================================================
__global__ __launch_bounds__(256) void aggregate_k(const float* __restrict__ h,
                                                   const int* __restrict__ off,
                                                   const int* __restrict__ eidx,
                                                   float* __restrict__ agg){
  const int node = blockIdx.x * 2 + (threadIdx.x >> 7);
  const int c = threadIdx.x & 127;
  if (node >= NODES) return;
  const int o0 = off[node], o1 = off[node + 1];
  const int d  = o1 - o0;
  float s = 0.f, ss = 0.f, mn = INFINITY, mx = -INFINITY;
  for (int k = o0; k < o1; k++){
    float vv = h[(size_t)eidx[k] * HDIM + c];
    s += vv; ss += vv * vv;
    mn = fminf(mn, vv); mx = fmaxf(mx, vv);
  }
  const float degc = fmaxf((float)d, 1.f);
  const float mean = s / degc;
  const float msq  = ss / degc;
  const float sd   = sqrtf(fmaxf(msq - mean * mean, 0.f) + EPS_STD);
  if (d == 0){ mn = 0.f; mx = 0.f; }
  float* a = agg + (size_t)node * 512;
  a[c]       = mean;
  a[128 + c] = mn;
  a[256 + c] = mx;
  a[384 + c] = sd;
}

// ---------------- BN + residual ----------------
__global__ __launch_bounds__(256) void bn_stats_k(const float* __restrict__ out2, float* mu, float* var){
  __shared__ float sh1[256], sh2[256];
  int c = blockIdx.x;
  float s = 0.f, ss = 0.f;
  for (int r = threadIdx.x; r < NODES; r += 256){
    float v = out2[(size_t)r * HDIM + c];
    s += v; ss += v * v;
  }
  sh1[threadIdx.x] = s; sh2[threadIdx.x] = ss;
  __syncthreads();
  for (int o = 128; o > 0; o >>= 1){
    if (threadIdx.x < o){ sh1[threadIdx.x] += sh1[threadIdx.x + o]; sh2[threadIdx.x] += sh2[threadIdx.x + o]; }
    __syncthreads();
  }
  if (threadIdx.x == 0){
    float m = sh1[0] / (float)NODES;
    mu[c] = m;
    var[c] = sh2[0] / (float)NODES - m * m;
  }
}

__global__ void xh_update_k(float* __restrict__ xh, const float* __restrict__ out2,
                            const float* __restrict__ mu, const float* __restrict__ var,
                            const float* __restrict__ gamma, const float* __restrict__ beta){
  int i = blockIdx.x * 256 + threadIdx.x;
  if (i >= NODES * HDIM) return;
  int c = i & 127;
  float bn = gamma[c] * (out2[i] - mu[c]) * rsqrtf(var[c] + EPS_BN) + beta[c];
  xh[i] = (xh[i] + fmaxf(bn, 0.f)) * 0.5f;
}

// ---------------- misc small kernels ----------------
__global__ void copy_k(float* __restrict__ d, const float* __restrict__ s, int n){
  int i = blockIdx.x * 256 + threadIdx.x;
  if (i < n) d[i] = s[i];
}
// bout[j] = badd[j] + sum_k bin[k] * W[k*128 + j]
__global__ void bias_comb_k(const float* __restrict__ bin, const float* __restrict__ W,
                            const float* __restrict__ badd, float* __restrict__ bout){
  int j = threadIdx.x;
  float s = badd[j];
  for (int k = 0; k < HDIM; k++) s = fmaf(bin[k], W[(size_t)k * HDIM + j], s);
  bout[j] = s;
}

// ===========================================================================
extern "C" void kernel_launch(void* const* d_in, const int* in_sizes, int n_in,
                              void* d_out, int out_size, void* d_ws, size_t ws_size,
                              hipStream_t stream) {
  const float* x      = (const float*)d_in[0];
  const int*   ei     = (const int*)  d_in[1];
  const float* ea     = (const float*)d_in[2];
  const float* W_node = (const float*)d_in[3];
  const float* b_node = (const float*)d_in[4];
  const float* W_edge = (const float*)d_in[5];
  const float* b_edge = (const float*)d_in[6];
  const float* W_ee   = (const float*)d_in[7];
  const float* b_ee   = (const float*)d_in[8];
  const float* W_pre  = (const float*)d_in[9];
  const float* b_pre  = (const float*)d_in[10];
  const float* W_post = (const float*)d_in[11];
  const float* b_post = (const float*)d_in[12];
  const float* W_lin  = (const float*)d_in[13];
  const float* b_lin  = (const float*)d_in[14];
  const float* gamma  = (const float*)d_in[15];
  const float* beta   = (const float*)d_in[16];
  const float* We1    = (const float*)d_in[17];
  const float* be1    = (const float*)d_in[18];
  const float* We2    = (const float*)d_in[19];
  const float* be2    = (const float*)d_in[20];

  const int* src = ei;
  const int* dst = ei + EDGES;

  float* xh = (float*)d_out;
  float* e  = xh + (size_t)NODES * HDIM;

  // ---- workspace bump allocator (64B aligned regions) ----
  char* wp = (char*)d_ws;
  auto alloc = [&](size_t bytes) -> char* {
    char* r = wp;
    wp += (bytes + 63) & ~(size_t)63;
    return r;
  };
  float* h     = (float*)alloc((size_t)EDGES * HDIM * 4);
  float* agg   = (float*)alloc((size_t)NODES * 512 * 4);
  float* out2  = (float*)alloc((size_t)NODES * HDIM * 4);
  int*   cnt    = (int*)alloc(NODES * 4);
  int*   cursor = (int*)alloc(NODES * 4);
  int*   off    = (int*)alloc((NODES + 1) * 4);
  int*   eidx   = (int*)alloc(EDGES * 4);
  float* fdeg = (float*)alloc(NODES * 4);
  float* invf = (float*)alloc(NODES * 4);
  float* Wc1  = (float*)alloc(384 * HDIM * 4);     // [Wp1;Wp2;W_ee@Wp3]
  float* Wc2  = (float*)alloc(1664 * HDIM * 4);    // W_post@W_lin
  float* bc1  = (float*)alloc(HDIM * 4);
  float* bc2  = (float*)alloc(HDIM * 4);
  float* mu   = (float*)alloc(HDIM * 4);
  float* var  = (float*)alloc(HDIM * 4);
  auto allocS = [&](int K) -> unsigned short* { return (unsigned short*)alloc((size_t)K * HDIM * 2); };
  unsigned short* BpNh = allocS(64);   unsigned short* BpNl = allocS(64);
  unsigned short* BpEh = allocS(32);   unsigned short* BpEl = allocS(32);
  unsigned short* Bp1h = allocS(384);  unsigned short* Bp1l = allocS(384);
  unsigned short* Bp2h = allocS(1664); unsigned short* Bp2l = allocS(1664);
  unsigned short* Bp3h = allocS(384);  unsigned short* Bp3l = allocS(384);
  unsigned short* Bp4h = allocS(128);  unsigned short* Bp4l = allocS(128);

  dim3 blk(256);
  dim3 blk512(512);
  auto mgrid = [](int M){ return dim3(1, (M + 127) / 128); };
  auto bgrid = [](int K){ return dim3((K / 32) * 8); };

  GArgs g{};

  // ---- once-per-call prep: degrees + CSR over dst ----
  deg_init_k <<<(NODES + 255) / 256, blk, 0, stream>>>(cnt, cursor);
  deg_count_k<<<(EDGES + 255) / 256, blk, 0, stream>>>(dst, cnt);
  deg_fin_k  <<<(NODES + 255) / 256, blk, 0, stream>>>(cnt, fdeg, invf);
  scan_k     <<<1, blk, 0, stream>>>(cnt, off);
  csr_fill_k <<<(EDGES + 255) / 256, blk, 0, stream>>>(dst, off, cursor, eidx);

  bprep_k<<<bgrid(FDIM), 64, 0, stream>>>(W_node, BpNh, BpNl);
  bprep_k<<<bgrid(DDIM), 64, 0, stream>>>(W_edge, BpEh, BpEl);

  // xh = x @ W_node + b_node
  g = GArgs{}; g.A = x; g.Bph = BpNh; g.Bpl = BpNl; g.bias = b_node; g.C = xh;
  g.M = NODES; g.K = FDIM;
  mgemm_k<0,0><<<mgrid(NODES), blk512, 0, stream>>>(g);

  // e = edge_attr @ W_edge + b_edge
  g = GArgs{}; g.A = ea; g.Bph = BpEh; g.Bpl = BpEl; g.bias = b_edge; g.C = e;
  g.M = EDGES; g.K = DDIM;
  mgemm_k<0,0><<<mgrid(EDGES), blk512, 0, stream>>>(g);

  for (int l = 0; l < 2; l++){
    const float* W_ee_l   = W_ee   + (size_t)l * HDIM * HDIM;
    const float* b_ee_l   = b_ee   + l * HDIM;
    const float* W_pre_l  = W_pre  + (size_t)l * 3 * HDIM * HDIM;
    const float* b_pre_l  = b_pre  + l * HDIM;
    const float* W_post_l = W_post + (size_t)l * 13 * HDIM * HDIM;
    const float* b_post_l = b_post + l * HDIM;
    const float* W_lin_l  = W_lin  + (size_t)l * HDIM * HDIM;
    const float* b_lin_l  = b_lin  + l * HDIM;
    const float* gamma_l  = gamma  + l * HDIM;
    const float* beta_l   = beta   + l * HDIM;
    const float* We1_l    = We1    + (size_t)l * 3 * HDIM * HDIM;
    const float* be1_l    = be1    + l * HDIM;
    const float* We2_l    = We2    + (size_t)l * HDIM * HDIM;
    const float* be2_l    = be2    + l * HDIM;
    const float* Wp3      = W_pre_l + (size_t)2 * HDIM * HDIM;  // rows 256..383

    // Wc1 = [Wp1;Wp2 ; W_ee @ Wp3],  bc1 = b_pre + b_ee@Wp3
    copy_k<<<(2 * HDIM * HDIM + 255) / 256, blk, 0, stream>>>(Wc1, W_pre_l, 2 * HDIM * HDIM);
    g = GArgs{}; g.A = W_ee_l; g.B = Wp3; g.C = Wc1 + (size_t)2 * HDIM * HDIM;
    g.M = HDIM; g.K = HDIM;
    gemm_k<0,0><<<dim3(2, 2), blk, 0, stream>>>(g);
    bias_comb_k<<<1, HDIM, 0, stream>>>(b_ee_l, Wp3, b_pre_l, bc1);
    bprep_k<<<bgrid(3 * HDIM), 64, 0, stream>>>(Wc1, Bp1h, Bp1l);

    // h = [xh[dst], xh[src], e] @ Wc1 + bc1
    g = GArgs{}; g.A = e; g.s0 = xh; g.s1 = xh; g.i0 = dst; g.i1 = src;
    g.Bph = Bp1h; g.Bpl = Bp1l; g.bias = bc1; g.C = h; g.M = EDGES; g.K = 3 * HDIM;
    mgemm_k<1,0><<<mgrid(EDGES), blk512, 0, stream>>>(g);

    // CSR multi-aggregation (fused finalize): agg = [mean|min|max|std]
    aggregate_k<<<(NODES + 1) / 2, blk, 0, stream>>>(h, off, eidx, agg);

    // Wc2 = W_post @ W_lin, bc2 = b_lin + b_post@W_lin
    g = GArgs{}; g.A = W_post_l; g.B = W_lin_l; g.C = Wc2; g.M = 13 * HDIM; g.K = HDIM;
    gemm_k<0,0><<<dim3(2, 26), blk, 0, stream>>>(g);
    bias_comb_k<<<1, HDIM, 0, stream>>>(b_post_l, W_lin_l, b_lin_l, bc2);
    bprep_k<<<bgrid(13 * HDIM), 64, 0, stream>>>(Wc2, Bp2h, Bp2l);

    // out2 = [xh, agg, agg*f, agg/f] @ Wc2 + bc2
    g = GArgs{}; g.A = xh; g.agg = agg; g.fs = fdeg; g.invfs = invf;
    g.Bph = Bp2h; g.Bpl = Bp2l; g.bias = bc2; g.C = out2; g.M = NODES; g.K = 13 * HDIM;
    mgemm_k<2,0><<<mgrid(NODES), blk512, 0, stream>>>(g);

    // BN + residual relu
    bn_stats_k<<<HDIM, blk, 0, stream>>>(out2, mu, var);
    xh_update_k<<<(NODES * HDIM + 255) / 256, blk, 0, stream>>>(xh, out2, mu, var, gamma_l, beta_l);

    // t1 = relu([xh[src], xh[dst], e] @ We1 + be1)   (t1 reuses h)
    bprep_k<<<bgrid(3 * HDIM), 64, 0, stream>>>(We1_l, Bp3h, Bp3l);
    g = GArgs{}; g.A = e; g.s0 = xh; g.s1 = xh; g.i0 = src; g.i1 = dst;
    g.Bph = Bp3h; g.Bpl = Bp3l; g.bias = be1_l; g.C = h; g.M = EDGES; g.K = 3 * HDIM;
    mgemm_k<1,1><<<mgrid(EDGES), blk512, 0, stream>>>(g);

    // e += 0.5 * (t1 @ We2 + be2)
    bprep_k<<<bgrid(HDIM), 64, 0, stream>>>(We2_l, Bp4h, Bp4l);
    g = GArgs{}; g.A = h; g.Bph = Bp4h; g.Bpl = Bp4l; g.bias = be2_l; g.C = e;
    g.M = EDGES; g.K = HDIM;
    mgemm_k<0,2><<<mgrid(EDGES), blk512, 0, stream>>>(g);
  }
}

// Round 5
// 851.448 us; speedup vs baseline: 1.3176x; 1.3176x over previous
//
#include <hip/hip_runtime.h>

// PNA GNN (2 layers) on MI355X — bf16x3 MFMA GEMMs, LDS-staged B, fused edge MLP.
#define NODES 10000
#define EDGES 160000
#define FDIM 64
#define DDIM 32
#define HDIM 128
#define AVG_DEG_LOG 2.8332133440562162f   // log(17)
#define EPS_BN 1e-5f
#define EPS_STD 1e-5f

typedef short bf16x8 __attribute__((ext_vector_type(8)));   // 8 bf16 (4 VGPRs)
typedef float f32x4  __attribute__((ext_vector_type(4)));   // 4 fp32

struct GArgs {
  const float* A;
  const float* s0;
  const float* s1;
  const int*   i0;
  const int*   i1;
  const float* agg;
  const float* fs;
  const float* invfs;
  const float* B;             // fp32 B for the small weight-combine GEMM
  const unsigned short* Bph;  // prepped bf16-hi fragments (GEMM1)
  const unsigned short* Bpl;  // prepped bf16-lo fragments
  const unsigned short* B2h;  // prepped fragments for fused GEMM2
  const unsigned short* B2l;
  const float* bias;
  const float* bias2;
  float*       C;
  int M, K;
};

// ---------------- bf16 helpers ----------------
__device__ __forceinline__ unsigned short f2bf(float x){   // round-to-nearest-even
  unsigned u = __float_as_uint(x);
  return (unsigned short)((u + 0x7FFFu + ((u >> 16) & 1u)) >> 16);
}
__device__ __forceinline__ float bf2f(unsigned short h){
  return __uint_as_float(((unsigned)h) << 16);
}
__device__ __forceinline__ void split2(float x, unsigned short& h, unsigned short& l){
  const unsigned u = __float_as_uint(x);
  h = (unsigned short)(u >> 16);                             // trunc hi
  const float rem = x - __uint_as_float(u & 0xFFFF0000u);
  l = (unsigned short)(__float_as_uint(rem) >> 16);          // trunc lo
}

#define GLD16(src, dst) __builtin_amdgcn_global_load_lds( \
    (const __attribute__((address_space(1))) void*)(src), \
    (__attribute__((address_space(3))) void*)(dst), 16, 0, 0)

#define ASTR 48   // shorts per LDS A row: 96 B stride, 16B-aligned b128 rows

// ===========================================================================
// MFMA GEMM: C[M,128] = gatherA[M,K] @ W[K,128] + bias, bf16 hi/lo split
// (3 MFMAs: ah*bh + ah*bl + al*bh; trunc split, rel err ~2^-16).
// 512 threads (8 waves): rq=w>>1 row quarter, ch=w&1 col half.
// BM=128 (MF=2) or 64 (MF=1). BK=32. A: reg dist-2 -> LDS dbuf.
// B: prepped global -> LDS dbuf via global_load_lds, 1 step ahead.
// AMODE 0: direct [M,K]; 1: [s0[i0], s1[i1], A]; 2: [A | agg | agg*f | agg/f]
// EPI 0: store; 1: relu-store; 2: C += 0.5*(acc+bias).
// ===========================================================================
template<int BM, int AMODE, int EPI>
__global__ __launch_bounds__(512, 4) void mgemm_k(GArgs g){
  constexpr int MF = BM / 64;
  constexpr int NV = MF;                 // float4s per thread per stage
  __shared__ unsigned short Ah[2][BM * ASTR];
  __shared__ unsigned short Al[2][BM * ASTR];
  __shared__ unsigned short Bh[2][4096];
  __shared__ unsigned short Bl[2][4096];
  const int tid  = threadIdx.x;
  const int row0 = blockIdx.y * BM;
  const int wave = tid >> 6, lane = tid & 63;
  const int rq = wave >> 1, ch = wave & 1;
  const int lrow = lane & 15, lk = lane >> 4;

  const int srow = (BM == 128) ? (tid >> 2) : (tid >> 3);
  const int c0   = (BM == 128) ? ((tid & 3) << 3) : ((tid & 7) << 2);
  const int gr   = row0 + srow;
  const bool valid = gr < g.M;
  const int gi = valid ? gr : 0;
  const float* p0; const float* p1; const float* p2;
  float f1 = 1.f, f2 = 1.f;
  if constexpr (AMODE == 0){
    p0 = g.A + (size_t)gi * g.K; p1 = p0; p2 = p0;
  } else if constexpr (AMODE == 1){
    p0 = g.s0 + (size_t)g.i0[gi] * HDIM;
    p1 = g.s1 + (size_t)g.i1[gi] * HDIM;
    p2 = g.A  + (size_t)gi * HDIM;
  } else {
    p0 = g.A   + (size_t)gi * HDIM;
    p1 = g.agg + (size_t)gi * 512;
    p2 = p1;
    f1 = g.fs[gi]; f2 = g.invfs[gi];
  }

  auto ldA = [&](int k0, float4* v){
    if (!valid){
      #pragma unroll
      for (int q = 0; q < NV; q++) v[q] = make_float4(0.f,0.f,0.f,0.f);
      return;
    }
    const int kk = k0 + c0;
    const float* p; float sc = 1.f;
    if constexpr (AMODE == 0){
      p = p0 + kk;
    } else if constexpr (AMODE == 1){
      p = (kk < HDIM) ? (p0 + kk) : (kk < 2*HDIM) ? (p1 + kk - HDIM) : (p2 + kk - 2*HDIM);
    } else {
      if (kk < HDIM){ p = p0 + kk; }
      else {
        const int q = kk - HDIM;
        p = p1 + (q & 511);
        const int seg = q >> 9;
        sc = (seg == 0) ? 1.f : (seg == 1) ? f1 : f2;
      }
    }
    #pragma unroll
    for (int q = 0; q < NV; q++) v[q] = ((const float4*)p)[q];
    if constexpr (AMODE == 2){
      if (sc != 1.f){
        #pragma unroll
        for (int q = 0; q < NV; q++){
          v[q].x *= sc; v[q].y *= sc; v[q].z *= sc; v[q].w *= sc;
        }
      }
    }
  };

  auto stA = [&](int buf, const float4* v){
    const int base = srow * ASTR + c0;
    #pragma unroll
    for (int q = 0; q < NV; q++){
      const float xs[4] = {v[q].x, v[q].y, v[q].z, v[q].w};
      ushort4 h4, l4;
      split2(xs[0], h4.x, l4.x); split2(xs[1], h4.y, l4.y);
      split2(xs[2], h4.z, l4.z); split2(xs[3], h4.w, l4.w);
      *(ushort4*)&Ah[buf][base + q*4] = h4;
      *(ushort4*)&Al[buf][base + q*4] = l4;
    }
  };

  auto gldB = [&](int s, int buf){
    const unsigned short* sh = g.Bph + (size_t)s * 4096 + tid * 8;
    const unsigned short* sl = g.Bpl + (size_t)s * 4096 + tid * 8;
    char* dh = (char*)&Bh[buf][0] + (tid >> 6) * 1024;
    char* dl = (char*)&Bl[buf][0] + (tid >> 6) * 1024;
    GLD16(sh, dh);
    GLD16(sl, dl);
  };

  const int nsteps = g.K >> 5;
  float4 va[2], wa[2];
  gldB(0, 0);
  ldA(0, va); stA(0, va);
  if (nsteps > 1) ldA(32, wa);
  __syncthreads();

  f32x4 acc[MF][4] = {};

  for (int s = 0; s < nsteps; s++){
    const int cur = s & 1;
    if (s + 1 < nsteps){
      gldB(s + 1, cur ^ 1);
      stA(cur ^ 1, wa);
      if (s + 2 < nsteps) ldA((s + 2) << 5, wa);
    }
    bf16x8 bh[4], bl[4];
    #pragma unroll
    for (int nf = 0; nf < 4; nf++){
      bh[nf] = *(const bf16x8*)&Bh[cur][(ch*4 + nf)*512 + lane*8];
      bl[nf] = *(const bf16x8*)&Bl[cur][(ch*4 + nf)*512 + lane*8];
    }
    #pragma unroll
    for (int mf = 0; mf < MF; mf++){
      const int ao = (rq*(16*MF) + mf*16 + lrow) * ASTR + lk * 8;
      bf16x8 ah  = *(const bf16x8*)&Ah[cur][ao];
      bf16x8 alo = *(const bf16x8*)&Al[cur][ao];
      #pragma unroll
      for (int nf = 0; nf < 4; nf++){
        acc[mf][nf] = __builtin_amdgcn_mfma_f32_16x16x32_bf16(ah,  bh[nf], acc[mf][nf], 0, 0, 0);
        acc[mf][nf] = __builtin_amdgcn_mfma_f32_16x16x32_bf16(ah,  bl[nf], acc[mf][nf], 0, 0, 0);
        acc[mf][nf] = __builtin_amdgcn_mfma_f32_16x16x32_bf16(alo, bh[nf], acc[mf][nf], 0, 0, 0);
      }
    }
    __syncthreads();
  }

  #pragma unroll
  for (int mf = 0; mf < MF; mf++){
    #pragma unroll
    for (int nf = 0; nf < 4; nf++){
      const int col = ch*64 + nf*16 + lrow;
      const float b = g.bias[col];
      #pragma unroll
      for (int j = 0; j < 4; j++){
        const int r = row0 + rq*(16*MF) + mf*16 + lk*4 + j;
        if (r < g.M){
          float val = acc[mf][nf][j] + b;
          if constexpr (EPI == 1) val = fmaxf(val, 0.f);
          float* cp = g.C + (size_t)r * HDIM + col;
          if constexpr (EPI == 2) val = *cp + 0.5f * val;
          *cp = val;
        }
      }
    }
  }
}

// ===========================================================================
// Fused edge MLP: e += 0.5*(relu([xh[src],xh[dst],e]@We1+be1)@We2 + be2).
// GEMM1: K=384 (12 steps), B-frags from L2; t1 tile -> LDS (bf16 hi/lo,
// aliases the A-staging buffer). GEMM2: K=128 (4 steps), no barriers.
// ===========================================================================
#define TSTR 136   // shorts per t1 row (272 B, 16B-aligned, odd*16 stride)

__global__ __launch_bounds__(512, 4) void fused_e_k(GArgs g){
  __shared__ unsigned short U[34816];   // 69632 B
  unsigned short* AhB = U;              // [2][128*ASTR] = 12288 shorts
  unsigned short* AlB = U + 12288;      // next 12288
  unsigned short* Th  = U;              // [128][TSTR] = 17408 shorts
  unsigned short* Tl  = U + 17408;
  const int tid  = threadIdx.x;
  const int row0 = blockIdx.y * 128;
  const int wave = tid >> 6, lane = tid & 63;
  const int rq = wave >> 1, ch = wave & 1;
  const int lrow = lane & 15, lk = lane >> 4;

  const int srow = tid >> 2;
  const int c0   = (tid & 3) << 3;
  const int gr   = row0 + srow;
  const float* p0 = g.s0 + (size_t)g.i0[gr] * HDIM;
  const float* p1 = g.s1 + (size_t)g.i1[gr] * HDIM;
  const float* p2 = g.A  + (size_t)gr * HDIM;

  auto ldA = [&](int k0, float4* v){
    const int kk = k0 + c0;
    const float* p = (kk < HDIM) ? (p0 + kk)
                   : (kk < 2*HDIM) ? (p1 + kk - HDIM) : (p2 + kk - 2*HDIM);
    v[0] = ((const float4*)p)[0]; v[1] = ((const float4*)p)[1];
  };
  auto stA = [&](int buf, const float4* v){
    const int base = buf * 6144 + srow * ASTR + c0;
    #pragma unroll
    for (int q = 0; q < 2; q++){
      const float xs[4] = {v[q].x, v[q].y, v[q].z, v[q].w};
      ushort4 h4, l4;
      split2(xs[0], h4.x, l4.x); split2(xs[1], h4.y, l4.y);
      split2(xs[2], h4.z, l4.z); split2(xs[3], h4.w, l4.w);
      *(ushort4*)&AhB[base + q*4] = h4;
      *(ushort4*)&AlB[base + q*4] = l4;
    }
  };

  float4 va[2], wa[2];
  ldA(0, va); stA(0, va);
  ldA(32, wa);
  __syncthreads();

  f32x4 acc1[2][4] = {};
  for (int s = 0; s < 12; s++){
    const int cur = s & 1;
    bf16x8 bh[4], bl[4];
    const size_t bbase = ((size_t)s * 8 + ch * 4) * 512 + (size_t)lane * 8;
    #pragma unroll
    for (int nf = 0; nf < 4; nf++){
      bh[nf] = *(const bf16x8*)(g.Bph + bbase + (size_t)nf * 512);
      bl[nf] = *(const bf16x8*)(g.Bpl + bbase + (size_t)nf * 512);
    }
    if (s + 1 < 12){
      stA(cur ^ 1, wa);
      if (s + 2 < 12) ldA((s + 2) << 5, wa);
    }
    #pragma unroll
    for (int mf = 0; mf < 2; mf++){
      const int ao = cur * 6144 + (rq*32 + mf*16 + lrow) * ASTR + lk * 8;
      bf16x8 ah  = *(const bf16x8*)&AhB[ao];
      bf16x8 alo = *(const bf16x8*)&AlB[ao];
      #pragma unroll
      for (int nf = 0; nf < 4; nf++){
        acc1[mf][nf] = __builtin_amdgcn_mfma_f32_16x16x32_bf16(ah,  bh[nf], acc1[mf][nf], 0, 0, 0);
        acc1[mf][nf] = __builtin_amdgcn_mfma_f32_16x16x32_bf16(ah,  bl[nf], acc1[mf][nf], 0, 0, 0);
        acc1[mf][nf] = __builtin_amdgcn_mfma_f32_16x16x32_bf16(alo, bh[nf], acc1[mf][nf], 0, 0, 0);
      }
    }
    __syncthreads();
  }

  // epilogue1: t1 = relu(acc1 + be1) -> LDS (hi/lo), aliasing A-stage region
  #pragma unroll
  for (int mf = 0; mf < 2; mf++){
    #pragma unroll
    for (int nf = 0; nf < 4; nf++){
      const int col = ch*64 + nf*16 + lrow;
      const float b = g.bias[col];
      #pragma unroll
      for (int j = 0; j < 4; j++){
        const int row = rq*32 + mf*16 + lk*4 + j;
        const float val = fmaxf(acc1[mf][nf][j] + b, 0.f);
        unsigned short h, l;
        split2(val, h, l);
        Th[row * TSTR + col] = h;
        Tl[row * TSTR + col] = l;
      }
    }
  }
  __syncthreads();

  // GEMM2: acc2 = t1 @ We2 (K=128, 4 steps, all from LDS/L2, no barriers)
  f32x4 acc2[2][4] = {};
  for (int s2 = 0; s2 < 4; s2++){
    bf16x8 bh[4], bl[4];
    const size_t bbase = ((size_t)s2 * 8 + ch * 4) * 512 + (size_t)lane * 8;
    #pragma unroll
    for (int nf = 0; nf < 4; nf++){
      bh[nf] = *(const bf16x8*)(g.B2h + bbase + (size_t)nf * 512);
      bl[nf] = *(const bf16x8*)(g.B2l + bbase + (size_t)nf * 512);
    }
    #pragma unroll
    for (int mf = 0; mf < 2; mf++){
      const int ao = (rq*32 + mf*16 + lrow) * TSTR + s2*32 + lk*8;
      bf16x8 ah  = *(const bf16x8*)&Th[ao];
      bf16x8 alo = *(const bf16x8*)&Tl[ao];
      #pragma unroll
      for (int nf = 0; nf < 4; nf++){
        acc2[mf][nf] = __builtin_amdgcn_mfma_f32_16x16x32_bf16(ah,  bh[nf], acc2[mf][nf], 0, 0, 0);
        acc2[mf][nf] = __builtin_amdgcn_mfma_f32_16x16x32_bf16(ah,  bl[nf], acc2[mf][nf], 0, 0, 0);
        acc2[mf][nf] = __builtin_amdgcn_mfma_f32_16x16x32_bf16(alo, bh[nf], acc2[mf][nf], 0, 0, 0);
      }
    }
  }

  // epilogue2: e += 0.5*(acc2 + be2)
  #pragma unroll
  for (int mf = 0; mf < 2; mf++){
    #pragma unroll
    for (int nf = 0; nf < 4; nf++){
      const int col = ch*64 + nf*16 + lrow;
      const float b = g.bias2[col];
      #pragma unroll
      for (int j = 0; j < 4; j++){
        const int r = row0 + rq*32 + mf*16 + lk*4 + j;
        if (r < g.M){
          float* cp = g.C + (size_t)r * HDIM + col;
          *cp = *cp + 0.5f * (acc2[mf][nf][j] + b);
        }
      }
    }
  }
}

// ===========================================================================
// B-prep: fp32 W[K,128] -> fragment-ordered bf16 hi/lo arrays (rounded split).
// ===========================================================================
__global__ void bprep_k(const float* __restrict__ W, unsigned short* __restrict__ Bph,
                        unsigned short* __restrict__ Bpl){
  const int bb = blockIdx.x;           // kq*8 + n
  const int kq = bb >> 3, n = bb & 7;
  const int l = threadIdx.x;           // 64
  const int colg = n*16 + (l & 15);
  const int krow = kq*32 + (l >> 4)*8;
  float vv[8];
  #pragma unroll
  for (int i = 0; i < 8; i++) vv[i] = W[(size_t)(krow + i) * HDIM + colg];
  unsigned short h[8], lo[8];
  #pragma unroll
  for (int i = 0; i < 8; i++){
    h[i]  = f2bf(vv[i]);
    lo[i] = f2bf(vv[i] - bf2f(h[i]));
  }
  const size_t o = ((size_t)bb * 64 + l) * 8;
  #pragma unroll
  for (int i = 0; i < 8; i++){ Bph[o+i] = h[i]; Bpl[o+i] = lo[i]; }
}

// ===========================================================================
// Small fp32 tiled GEMM for weight combining (M<=1664, K=128, N=128).
// ===========================================================================
__global__ __launch_bounds__(256) void gemm_k(GArgs g){
  __shared__ float As[16][68];
  __shared__ float Bs[16][68];
  const int tid = threadIdx.x;
  const int tx = tid & 15, ty = tid >> 4;
  const int row0 = blockIdx.y * 64, col0 = blockIdx.x * 64;
  float acc[4][4] = {};
  for (int k0 = 0; k0 < g.K; k0 += 16){
    #pragma unroll
    for (int i = 0; i < 4; i++){
      int l = tid + i * 256;
      int ar = l >> 4, ak = l & 15;
      int gr = row0 + ar;
      float v = 0.f;
      if (gr < g.M) v = g.A[(size_t)gr * g.K + k0 + ak];
      As[ak][ar] = v;
    }
    #pragma unroll
    for (int i = 0; i < 4; i++){
      int l = tid + i * 256;
      int bn_ = l & 63, bk = l >> 6;
      Bs[bk][bn_] = g.B[(size_t)(k0 + bk) * HDIM + col0 + bn_];
    }
    __syncthreads();
    #pragma unroll
    for (int kk = 0; kk < 16; kk++){
      float a[4], b[4];
      #pragma unroll
      for (int j = 0; j < 4; j++) a[j] = As[kk][ty*4 + j];
      #pragma unroll
      for (int j = 0; j < 4; j++) b[j] = Bs[kk][tx*4 + j];
      #pragma unroll
      for (int ii = 0; ii < 4; ii++)
        #pragma unroll
        for (int jj = 0; jj < 4; jj++)
          acc[ii][jj] = fmaf(a[ii], b[jj], acc[ii][jj]);
    }
    __syncthreads();
  }
  #pragma unroll
  for (int ii = 0; ii < 4; ii++){
    int gr = row0 + ty*4 + ii;
    if (gr >= g.M) continue;
    #pragma unroll
    for (int jj = 0; jj < 4; jj++)
      g.C[(size_t)gr * HDIM + col0 + tx*4 + jj] = acc[ii][jj];
  }
}

// ===========================================================================
// CSR build over dst (constant across layers): deg count -> scan -> fill.
// ===========================================================================
__global__ void deg_init_k(int* cnt, int* cursor){
  int i = blockIdx.x * 256 + threadIdx.x;
  if (i < NODES){ cnt[i] = 0; cursor[i] = 0; }
}
__global__ void deg_count_k(const int* __restrict__ dst, int* cnt){
  int e = blockIdx.x * 256 + threadIdx.x;
  if (e < EDGES) atomicAdd(&cnt[dst[e]], 1);
}
__global__ void deg_fin_k(const int* __restrict__ cnt, float* fdeg, float* invf){
  int i = blockIdx.x * 256 + threadIdx.x;
  if (i < NODES){
    float d = fmaxf((float)cnt[i], 1.f);
    float f = logf(d + 1.f) / AVG_DEG_LOG;
    fdeg[i] = f;
    invf[i] = 1.f / f;
  }
}
__global__ __launch_bounds__(256) void scan_k(const int* __restrict__ cnt, int* __restrict__ off){
  __shared__ int sh[256];
  __shared__ int carry;
  if (threadIdx.x == 0) carry = 0;
  __syncthreads();
  for (int base = 0; base < NODES; base += 256){
    int i = base + threadIdx.x;
    int v = (i < NODES) ? cnt[i] : 0;
    sh[threadIdx.x] = v;
    __syncthreads();
    #pragma unroll
    for (int o = 1; o < 256; o <<= 1){
      int t = (threadIdx.x >= o) ? sh[threadIdx.x - o] : 0;
      __syncthreads();
      sh[threadIdx.x] += t;
      __syncthreads();
    }
    if (i < NODES) off[i] = carry + sh[threadIdx.x] - v;   // exclusive
    __syncthreads();
    if (threadIdx.x == 255) carry += sh[255];
    __syncthreads();
  }
  if (threadIdx.x == 0) off[NODES] = carry;
}
__global__ void csr_fill_k(const int* __restrict__ dst, const int* __restrict__ off,
                           int* cursor, int* __restrict__ eidx){
  int e = blockIdx.x * 256 + threadIdx.x;
  if (e < EDGES){
    int d = dst[e];
    int p = atomicAdd(&cursor[d], 1);
    eidx[off[d] + p] = e;
  }
}

// ===========================================================================
// CSR aggregation: block = 256 thr = 2 nodes x 128 cols. Fuses finalize.
// agg[node][0:512] = [mean | min | max | std]
// ===========================================================================
__global__ __launch_bounds__(256) void aggregate_k(const float* __restrict__ h,
                                                   const int* __restrict__ off,
                                                   const int* __restrict__ eidx,
                                                   float* __restrict__ agg){
  const int node = blockIdx.x * 2 + (threadIdx.x >> 7);
  const int c = threadIdx.x & 127;
  if (node >= NODES) return;
  const int o0 = off[node], o1 = off[node + 1];
  const int d  = o1 - o0;
  float s = 0.f, ss = 0.f, mn = INFINITY, mx = -INFINITY;
  for (int k = o0; k < o1; k++){
    float vv = h[(size_t)eidx[k] * HDIM + c];
    s += vv; ss += vv * vv;
    mn = fminf(mn, vv); mx = fmaxf(mx, vv);
  }
  const float degc = fmaxf((float)d, 1.f);
  const float mean = s / degc;
  const float msq  = ss / degc;
  const float sd   = sqrtf(fmaxf(msq - mean * mean, 0.f) + EPS_STD);
  if (d == 0){ mn = 0.f; mx = 0.f; }
  float* a = agg + (size_t)node * 512;
  a[c]       = mean;
  a[128 + c] = mn;
  a[256 + c] = mx;
  a[384 + c] = sd;
}

// ---------------- BN + residual ----------------
__global__ __launch_bounds__(256) void bn_stats_k(const float* __restrict__ out2, float* mu, float* var){
  __shared__ float sh1[256], sh2[256];
  int c = blockIdx.x;
  float s = 0.f, ss = 0.f;
  for (int r = threadIdx.x; r < NODES; r += 256){
    float v = out2[(size_t)r * HDIM + c];
    s += v; ss += v * v;
  }
  sh1[threadIdx.x] = s; sh2[threadIdx.x] = ss;
  __syncthreads();
  for (int o = 128; o > 0; o >>= 1){
    if (threadIdx.x < o){ sh1[threadIdx.x] += sh1[threadIdx.x + o]; sh2[threadIdx.x] += sh2[threadIdx.x + o]; }
    __syncthreads();
  }
  if (threadIdx.x == 0){
    float m = sh1[0] / (float)NODES;
    mu[c] = m;
    var[c] = sh2[0] / (float)NODES - m * m;
  }
}

__global__ void xh_update_k(float* __restrict__ xh, const float* __restrict__ out2,
                            const float* __restrict__ mu, const float* __restrict__ var,
                            const float* __restrict__ gamma, const float* __restrict__ beta){
  int i = blockIdx.x * 256 + threadIdx.x;
  if (i >= NODES * HDIM) return;
  int c = i & 127;
  float bn = gamma[c] * (out2[i] - mu[c]) * rsqrtf(var[c] + EPS_BN) + beta[c];
  xh[i] = (xh[i] + fmaxf(bn, 0.f)) * 0.5f;
}

// ---------------- misc small kernels ----------------
__global__ void copy_k(float* __restrict__ d, const float* __restrict__ s, int n){
  int i = blockIdx.x * 256 + threadIdx.x;
  if (i < n) d[i] = s[i];
}
__global__ void bias_comb_k(const float* __restrict__ bin, const float* __restrict__ W,
                            const float* __restrict__ badd, float* __restrict__ bout){
  int j = threadIdx.x;
  float s = badd[j];
  for (int k = 0; k < HDIM; k++) s = fmaf(bin[k], W[(size_t)k * HDIM + j], s);
  bout[j] = s;
}

// ===========================================================================
extern "C" void kernel_launch(void* const* d_in, const int* in_sizes, int n_in,
                              void* d_out, int out_size, void* d_ws, size_t ws_size,
                              hipStream_t stream) {
  const float* x      = (const float*)d_in[0];
  const int*   ei     = (const int*)  d_in[1];
  const float* ea     = (const float*)d_in[2];
  const float* W_node = (const float*)d_in[3];
  const float* b_node = (const float*)d_in[4];
  const float* W_edge = (const float*)d_in[5];
  const float* b_edge = (const float*)d_in[6];
  const float* W_ee   = (const float*)d_in[7];
  const float* b_ee   = (const float*)d_in[8];
  const float* W_pre  = (const float*)d_in[9];
  const float* b_pre  = (const float*)d_in[10];
  const float* W_post = (const float*)d_in[11];
  const float* b_post = (const float*)d_in[12];
  const float* W_lin  = (const float*)d_in[13];
  const float* b_lin  = (const float*)d_in[14];
  const float* gamma  = (const float*)d_in[15];
  const float* beta   = (const float*)d_in[16];
  const float* We1    = (const float*)d_in[17];
  const float* be1    = (const float*)d_in[18];
  const float* We2    = (const float*)d_in[19];
  const float* be2    = (const float*)d_in[20];

  const int* src = ei;
  const int* dst = ei + EDGES;

  float* xh = (float*)d_out;
  float* e  = xh + (size_t)NODES * HDIM;

  // ---- workspace bump allocator (64B aligned regions) ----
  char* wp = (char*)d_ws;
  auto alloc = [&](size_t bytes) -> char* {
    char* r = wp;
    wp += (bytes + 63) & ~(size_t)63;
    return r;
  };
  float* h     = (float*)alloc((size_t)EDGES * HDIM * 4);
  float* agg   = (float*)alloc((size_t)NODES * 512 * 4);
  float* out2  = (float*)alloc((size_t)NODES * HDIM * 4);
  int*   cnt    = (int*)alloc(NODES * 4);
  int*   cursor = (int*)alloc(NODES * 4);
  int*   off    = (int*)alloc((NODES + 1) * 4);
  int*   eidx   = (int*)alloc(EDGES * 4);
  float* fdeg = (float*)alloc(NODES * 4);
  float* invf = (float*)alloc(NODES * 4);
  float* Wc1  = (float*)alloc(384 * HDIM * 4);     // [Wp1;Wp2;W_ee@Wp3]
  float* Wc2  = (float*)alloc(1664 * HDIM * 4);    // W_post@W_lin
  float* bc1  = (float*)alloc(HDIM * 4);
  float* bc2  = (float*)alloc(HDIM * 4);
  float* mu   = (float*)alloc(HDIM * 4);
  float* var  = (float*)alloc(HDIM * 4);
  auto allocS = [&](int K) -> unsigned short* { return (unsigned short*)alloc((size_t)K * HDIM * 2); };
  unsigned short* BpNh = allocS(64);   unsigned short* BpNl = allocS(64);
  unsigned short* BpEh = allocS(32);   unsigned short* BpEl = allocS(32);
  unsigned short* Bp1h = allocS(384);  unsigned short* Bp1l = allocS(384);
  unsigned short* Bp2h = allocS(1664); unsigned short* Bp2l = allocS(1664);
  unsigned short* Bp3h = allocS(384);  unsigned short* Bp3l = allocS(384);
  unsigned short* Bp4h = allocS(128);  unsigned short* Bp4l = allocS(128);

  dim3 blk(256);
  dim3 blk512(512);
  auto bgrid = [](int K){ return dim3((K / 32) * 8); };

  GArgs g{};

  // ---- once-per-call prep: degrees + CSR over dst ----
  deg_init_k <<<(NODES + 255) / 256, blk, 0, stream>>>(cnt, cursor);
  deg_count_k<<<(EDGES + 255) / 256, blk, 0, stream>>>(dst, cnt);
  deg_fin_k  <<<(NODES + 255) / 256, blk, 0, stream>>>(cnt, fdeg, invf);
  scan_k     <<<1, blk, 0, stream>>>(cnt, off);
  csr_fill_k <<<(EDGES + 255) / 256, blk, 0, stream>>>(dst, off, cursor, eidx);

  bprep_k<<<bgrid(FDIM), 64, 0, stream>>>(W_node, BpNh, BpNl);
  bprep_k<<<bgrid(DDIM), 64, 0, stream>>>(W_edge, BpEh, BpEl);

  // xh = x @ W_node + b_node   (BM=64: 157 blocks)
  g = GArgs{}; g.A = x; g.Bph = BpNh; g.Bpl = BpNl; g.bias = b_node; g.C = xh;
  g.M = NODES; g.K = FDIM;
  mgemm_k<64,0,0><<<dim3(1, (NODES + 63) / 64), blk512, 0, stream>>>(g);

  // e = edge_attr @ W_edge + b_edge
  g = GArgs{}; g.A = ea; g.Bph = BpEh; g.Bpl = BpEl; g.bias = b_edge; g.C = e;
  g.M = EDGES; g.K = DDIM;
  mgemm_k<128,0,0><<<dim3(1, EDGES / 128), blk512, 0, stream>>>(g);

  for (int l = 0; l < 2; l++){
    const float* W_ee_l   = W_ee   + (size_t)l * HDIM * HDIM;
    const float* b_ee_l   = b_ee   + l * HDIM;
    const float* W_pre_l  = W_pre  + (size_t)l * 3 * HDIM * HDIM;
    const float* b_pre_l  = b_pre  + l * HDIM;
    const float* W_post_l = W_post + (size_t)l * 13 * HDIM * HDIM;
    const float* b_post_l = b_post + l * HDIM;
    const float* W_lin_l  = W_lin  + (size_t)l * HDIM * HDIM;
    const float* b_lin_l  = b_lin  + l * HDIM;
    const float* gamma_l  = gamma  + l * HDIM;
    const float* beta_l   = beta   + l * HDIM;
    const float* We1_l    = We1    + (size_t)l * 3 * HDIM * HDIM;
    const float* be1_l    = be1    + l * HDIM;
    const float* We2_l    = We2    + (size_t)l * HDIM * HDIM;
    const float* be2_l    = be2    + l * HDIM;
    const float* Wp3      = W_pre_l + (size_t)2 * HDIM * HDIM;  // rows 256..383

    // Wc1 = [Wp1;Wp2 ; W_ee @ Wp3],  bc1 = b_pre + b_ee@Wp3
    copy_k<<<(2 * HDIM * HDIM + 255) / 256, blk, 0, stream>>>(Wc1, W_pre_l, 2 * HDIM * HDIM);
    g = GArgs{}; g.A = W_ee_l; g.B = Wp3; g.C = Wc1 + (size_t)2 * HDIM * HDIM;
    g.M = HDIM; g.K = HDIM;
    gemm_k<<<dim3(2, 2), blk, 0, stream>>>(g);
    bias_comb_k<<<1, HDIM, 0, stream>>>(b_ee_l, Wp3, b_pre_l, bc1);
    bprep_k<<<bgrid(3 * HDIM), 64, 0, stream>>>(Wc1, Bp1h, Bp1l);

    // h = [xh[dst], xh[src], e] @ Wc1 + bc1
    g = GArgs{}; g.A = e; g.s0 = xh; g.s1 = xh; g.i0 = dst; g.i1 = src;
    g.Bph = Bp1h; g.Bpl = Bp1l; g.bias = bc1; g.C = h; g.M = EDGES; g.K = 3 * HDIM;
    mgemm_k<128,1,0><<<dim3(1, EDGES / 128), blk512, 0, stream>>>(g);

    // CSR multi-aggregation (fused finalize): agg = [mean|min|max|std]
    aggregate_k<<<(NODES + 1) / 2, blk, 0, stream>>>(h, off, eidx, agg);

    // Wc2 = W_post @ W_lin, bc2 = b_lin + b_post@W_lin
    g = GArgs{}; g.A = W_post_l; g.B = W_lin_l; g.C = Wc2; g.M = 13 * HDIM; g.K = HDIM;
    gemm_k<<<dim3(2, 26), blk, 0, stream>>>(g);
    bias_comb_k<<<1, HDIM, 0, stream>>>(b_post_l, W_lin_l, b_lin_l, bc2);
    bprep_k<<<bgrid(13 * HDIM), 64, 0, stream>>>(Wc2, Bp2h, Bp2l);

    // out2 = [xh, agg, agg*f, agg/f] @ Wc2 + bc2   (BM=64: 157 blocks)
    g = GArgs{}; g.A = xh; g.agg = agg; g.fs = fdeg; g.invfs = invf;
    g.Bph = Bp2h; g.Bpl = Bp2l; g.bias = bc2; g.C = out2; g.M = NODES; g.K = 13 * HDIM;
    mgemm_k<64,2,0><<<dim3(1, (NODES + 63) / 64), blk512, 0, stream>>>(g);

    // BN + residual relu
    bn_stats_k<<<HDIM, blk, 0, stream>>>(out2, mu, var);
    xh_update_k<<<(NODES * HDIM + 255) / 256, blk, 0, stream>>>(xh, out2, mu, var, gamma_l, beta_l);

    // fused edge MLP: e += 0.5*(relu([xh[src],xh[dst],e]@We1+be1)@We2+be2)
    bprep_k<<<bgrid(3 * HDIM), 64, 0, stream>>>(We1_l, Bp3h, Bp3l);
    bprep_k<<<bgrid(HDIM), 64, 0, stream>>>(We2_l, Bp4h, Bp4l);
    g = GArgs{}; g.A = e; g.s0 = xh; g.s1 = xh; g.i0 = src; g.i1 = dst;
    g.Bph = Bp3h; g.Bpl = Bp3l; g.B2h = Bp4h; g.B2l = Bp4l;
    g.bias = be1_l; g.bias2 = be2_l; g.C = e; g.M = EDGES; g.K = 3 * HDIM;
    fused_e_k<<<dim3(1, EDGES / 128), blk512, 0, stream>>>(g);
  }
}